// Round 6
// baseline (391.032 us; speedup 1.0000x reference)
//
#include <hip/hip_runtime.h>

#define NN 100000
#define NE 1600000
#define NG 1024
#define CPAD 4     // counter stride (ints). R8/R9: atomic-throughput-bound either way
#define MAXDEG 64  // padded CSR row; Poisson(16) -> P(deg>=64) ~ 1e-19 per node

// merged-setup grid: period-13 groups of 8 blocks (all 8 XCDs per group; R4/R5
// showed atomics must issue from all XCDs). Per period: 10 count groups + 3
// compute groups (count:compute block ratio 6250:1888 ~= 3.3).
#define GB_COUNT 6250   // NE/256 count blocks, 1 edge/thread
#define GB_Z     1563   // ceil(NN/64) Z-gemm blocks (also emits xb rows)
#define GB_BND   5
#define GB_PREP  320    // 5 matrices x 64 blocks
#define GB_ODD   (GB_Z + GB_BND + GB_PREP)  // 1888
#define GB_SETUP (79 * 13 * 8)  // 8216: 790 count groups, 237 compute groups

typedef __attribute__((ext_vector_type(8))) short bf16x8;
typedef __attribute__((ext_vector_type(4))) float f32x4;

__device__ __forceinline__ unsigned f2bf1(float f) {
  union { float f; unsigned u; } v; v.f = f;
  return (v.u + 0x7fffu + ((v.u >> 16) & 1u)) >> 16;  // RNE
}
__device__ __forceinline__ unsigned packbf2(float a, float b) {
  return f2bf1(a) | (f2bf1(b) << 16);
}
__device__ __forceinline__ float bflo(unsigned u) {
  union { unsigned u; float f; } v; v.u = u << 16; return v.f;
}
__device__ __forceinline__ float bfhi(unsigned u) {
  union { unsigned u; float f; } v; v.u = u & 0xffff0000u; return v.f;
}
__device__ __forceinline__ float bfs(unsigned short s) {
  union { unsigned u; float f; } v; v.u = ((unsigned)s) << 16; return v.f;
}

// accumulate 16 bf16 channels (two uint4 = 32B) into A[16]
#define ACC16(A, P0, P1)                                              \
  A[0] += bflo(P0.x); A[1] += bfhi(P0.x);                             \
  A[2] += bflo(P0.y); A[3] += bfhi(P0.y);                             \
  A[4] += bflo(P0.z); A[5] += bfhi(P0.z);                             \
  A[6] += bflo(P0.w); A[7] += bfhi(P0.w);                             \
  A[8] += bflo(P1.x); A[9] += bfhi(P1.x);                             \
  A[10] += bflo(P1.y); A[11] += bfhi(P1.y);                           \
  A[12] += bflo(P1.z); A[13] += bfhi(P1.z);                           \
  A[14] += bflo(P1.w); A[15] += bfhi(P1.w);

// accumulate 8 bf16 channels (one uint4 = 16B) into A[8]
#define ACC8(A, V)                                                    \
  A[0] += bflo(V.x); A[1] += bfhi(V.x);                               \
  A[2] += bflo(V.y); A[3] += bfhi(V.y);                               \
  A[4] += bflo(V.z); A[5] += bfhi(V.z);                               \
  A[6] += bflo(V.w); A[7] += bfhi(V.w);

// ---------------------- pre-pack c1_wr (K=64,N=128) B-frags for the Z-gemm --
__global__ __launch_bounds__(256) void k_prepz(const float* __restrict__ c1wr,
                                               unsigned short* __restrict__ pLZ) {
  int e = blockIdx.x * 256 + threadIdx.x;  // 64*128 = 8192
  if (e >= 64 * 128) return;
  int k = e >> 7, n = e & 127;
  int t = k >> 5, kq = (k >> 3) & 3, j = k & 7;
  int n0 = n >> 4, nl = n & 15;
  pLZ[((((n0 * 2 + t) * 64) + (kq * 16 + nl)) << 3) + j] =
      (unsigned short)f2bf1(c1wr[k * 128 + n]);
}

// ---------------------------------------------------------- merged setup ----
// count blocks: one atomic per edge does BOTH count and CSR slot assignment
// (padded csr rows -> no scan/fill dependency).
__global__ __launch_bounds__(256) void k_setup(
    const int* __restrict__ src, const int* __restrict__ dst,
    int* __restrict__ cnt, int* __restrict__ csr,
    const float* __restrict__ X, unsigned short* __restrict__ Xb,
    const int* __restrict__ batch, int* __restrict__ gstart,
    const unsigned short* __restrict__ pLZ, const float* __restrict__ c1bl,
    unsigned short* __restrict__ ZZ,
    const float* __restrict__ c1wl, const float* __restrict__ c1wr,
    const float* __restrict__ c2wl, const float* __restrict__ c2wr,
    const float* __restrict__ c3wl, const float* __restrict__ c3wr,
    const float* __restrict__ c4wl, const float* __restrict__ c4wr,
    unsigned short* __restrict__ pL1, unsigned short* __restrict__ pL2a,
    unsigned short* __restrict__ pL2b, unsigned short* __restrict__ pL3,
    unsigned short* __restrict__ pL4) {
  __shared__ __align__(16) char smem[64 * 66 * 4];  // Z-gemm sA/sC
  int b = blockIdx.x, tid = threadIdx.x;
  int g = b >> 3, i = b & 7;  // i spans all 8 XCDs within each group
  int p = g / 13, r = g - p * 13;

  if (r < 10) {  // ---- count + fill (atomic-bound; all XCDs issuing)
    int cb = (p * 10 + r) * 8 + i;
    if (cb >= GB_COUNT) return;
    int e = cb * 256 + tid;
    int d = dst[e];
    int s = src[e];
    int rk = atomicAdd(&cnt[(size_t)d * CPAD], 1);
    if (rk < MAXDEG) csr[d * MAXDEG + rk] = s;
    return;
  }
  int ob = (p * 3 + (r - 10)) * 8 + i;  // compute index
  if (ob >= GB_ODD) return;

  if (ob < GB_Z) {  // ---- Z-gemm: ZZ = x @ c1_wr + c1_bl; also emits xb rows
    unsigned short* sA = (unsigned short*)smem;
    float* sC = (float*)smem;
    const int m0 = ob * 64;
    // stage A (64 rows x 64 k, fp32 -> bf16 A-frags, K=64 layout) + xb write
#pragma unroll
    for (int l = 0; l < 2; ++l) {
      int c = tid + l * 256;  // 512 chunks
      int m = c >> 3, k8 = c & 7;
      int row = m0 + m;
      uint4 o = make_uint4(0, 0, 0, 0);
      if (row < NN) {
        const float4* xp = (const float4*)(X + (size_t)row * 64 + k8 * 8);
        float4 p0 = xp[0], p1 = xp[1];
        o.x = packbf2(p0.x, p0.y); o.y = packbf2(p0.z, p0.w);
        o.z = packbf2(p1.x, p1.y); o.w = packbf2(p1.z, p1.w);
        ((uint4*)(Xb + (size_t)row * 64))[k8] = o;  // fused x->bf16 emit
      }
      int wv = m >> 4, mr = m & 15, t = k8 >> 2, kq = k8 & 3;
      ((uint4*)sA)[(wv * 2 + t) * 64 + kq * 16 + mr] = o;
    }
    __syncthreads();
    const int w = tid >> 6, L = tid & 63;
    const bf16x8* Af = (const bf16x8*)sA;
    const bf16x8* Bf = (const bf16x8*)pLZ;
    f32x4 acc[8];
#pragma unroll
    for (int i2 = 0; i2 < 8; ++i2)
#pragma unroll
      for (int j = 0; j < 4; ++j) acc[i2][j] = 0.f;
#pragma unroll
    for (int t = 0; t < 2; ++t) {
      bf16x8 afr = Af[(w * 2 + t) * 64 + L];
#pragma unroll
      for (int n0 = 0; n0 < 8; ++n0) {
        bf16x8 bfr = Bf[(n0 * 2 + t) * 64 + L];
        acc[n0] = __builtin_amdgcn_mfma_f32_16x16x32_bf16(afr, bfr, acc[n0], 0, 0, 0);
      }
    }
    int rg = L >> 4, cl = L & 15;
#pragma unroll
    for (int half = 0; half < 2; ++half) {
      __syncthreads();
#pragma unroll
      for (int n0 = 0; n0 < 4; ++n0)
#pragma unroll
        for (int rr = 0; rr < 4; ++rr)
          sC[(w * 16 + rg * 4 + rr) * 66 + n0 * 16 + cl] = acc[half * 4 + n0][rr];
      __syncthreads();
#pragma unroll
      for (int it = 0; it < 2; ++it) {
        int c = tid + it * 256;
        int m = c >> 3, c8 = c & 7;
        int row = m0 + m;
        if (row < NN) {
          float v[8];
#pragma unroll
          for (int j = 0; j < 8; ++j)
            v[j] = sC[m * 66 + c8 * 8 + j] + c1bl[half * 64 + c8 * 8 + j];
          uint4 o;
          o.x = packbf2(v[0], v[1]); o.y = packbf2(v[2], v[3]);
          o.z = packbf2(v[4], v[5]); o.w = packbf2(v[6], v[7]);
          ((uint4*)(ZZ + (size_t)row * 128 + half * 64))[c8] = o;
        }
      }
    }
    return;
  }
  ob -= GB_Z;
  if (ob < GB_BND) {  // ---- graph bounds (sorted batch)
    int gg = ob * 256 + tid;
    if (gg > NG) return;
    int lo = 0, hi = NN;
    while (lo < hi) {
      int mid = (lo + hi) >> 1;
      if (batch[mid] < gg) lo = mid + 1; else hi = mid;
    }
    gstart[gg] = lo;
    return;
  }
  ob -= GB_BND;
  if (ob < GB_PREP) {  // ---- pack conv weights (K=128 B-frag layout)
    int yb = ob >> 6, xb2 = ob & 63;
    const float *WL, *WR; unsigned short* dstp; int N;
    if (yb == 0)      { WL = c1wl; WR = c1wr;           dstp = pL1;  N = 128; }
    else if (yb == 1) { WL = c2wl; WR = c2wl + 64 * 64; dstp = pL2a; N = 64; }
    else if (yb == 2) { WL = c2wr; WR = c2wr + 64 * 64; dstp = pL2b; N = 64; }
    else if (yb == 3) { WL = c3wl; WR = c3wr;           dstp = pL3;  N = 64; }
    else              { WL = c4wl; WR = c4wr;           dstp = pL4;  N = 64; }
    int e = xb2 * 256 + tid;
    if (e >= 128 * N) return;
    int k = e / N, n = e - k * N;
    float w = (k < 64) ? WL[k * N + n] : WR[(k - 64) * N + n];
    int t = k >> 5, kq = (k >> 3) & 3, j = k & 7;
    int n0 = n >> 4, nl = n & 15;
    dstp[((((n0 * 4 + t) * 64) + (kq * 16 + nl)) << 3) + j] =
        (unsigned short)f2bf1(w);
  }
}

// ---- in-block degree sort: bitonic over 64 (deg,slot) keys. Wave = 16 rows
// of similar degree afterwards -> gather loop divergence ~max->~mean.
// Output: skey[pos] = (deg<<6)|orig_slot, ascending by deg. Numerics-identical
// (per-row sum order unchanged; only row->tile-slot mapping permuted).
__device__ __forceinline__ void sort_deg(const int* __restrict__ cnt, int m0,
                                         int tid, short* skey) {
  if (tid < 64) {
    int row = m0 + tid;
    int dg = 0;
    if (row < NN) dg = min(cnt[(size_t)row * CPAD], MAXDEG);
    skey[tid] = (short)((dg << 6) | tid);
  }
  __syncthreads();
  for (int k = 2; k <= 64; k <<= 1) {
    for (int j = k >> 1; j > 0; j >>= 1) {
      if (tid < 64) {
        int pp = tid ^ j;
        if (pp > tid) {
          short a = skey[tid], b = skey[pp];
          bool up = ((tid & k) == 0);
          if ((a > b) == up) { skey[tid] = b; skey[pp] = a; }
        }
      }
      __syncthreads();
    }
  }
}

// ---------------------------- gather (layer-2 epilogue: relu(agg+b+Z)) ------
__global__ __launch_bounds__(256) void k_gather(
    const unsigned short* __restrict__ F, const int* __restrict__ csr,
    const int* __restrict__ cnt, const float* __restrict__ bias,
    const unsigned short* __restrict__ Z, unsigned short* __restrict__ out) {
  int idx = blockIdx.x * 256 + threadIdx.x;  // grid = NN*8 threads
  int n = idx >> 3, q = idx & 7;
  int deg = cnt[(size_t)n * CPAD];
  int degc = min(deg, MAXDEG);
  int beg = n * MAXDEG, end = beg + degc;
  float aA[8], aB[8];
#pragma unroll
  for (int c = 0; c < 8; ++c) { aA[c] = 0.f; aB[c] = 0.f; }
  int e = beg;
  for (; e + 8 <= end; e += 8) {  // 8 edges in flight, int4 index loads
    int4 s0 = *(const int4*)(csr + e);
    int4 s1 = *(const int4*)(csr + e + 4);
    uint4 v0 = ((const uint4*)(F + (size_t)s0.x * 64))[q];
    uint4 v1 = ((const uint4*)(F + (size_t)s0.y * 64))[q];
    uint4 v2 = ((const uint4*)(F + (size_t)s0.z * 64))[q];
    uint4 v3 = ((const uint4*)(F + (size_t)s0.w * 64))[q];
    uint4 v4 = ((const uint4*)(F + (size_t)s1.x * 64))[q];
    uint4 v5 = ((const uint4*)(F + (size_t)s1.y * 64))[q];
    uint4 v6 = ((const uint4*)(F + (size_t)s1.z * 64))[q];
    uint4 v7 = ((const uint4*)(F + (size_t)s1.w * 64))[q];
    ACC8(aA, v0) ACC8(aB, v1) ACC8(aA, v2) ACC8(aB, v3)
    ACC8(aA, v4) ACC8(aB, v5) ACC8(aA, v6) ACC8(aB, v7)
  }
  if (e + 4 <= end) {
    int4 s0 = *(const int4*)(csr + e);
    uint4 v0 = ((const uint4*)(F + (size_t)s0.x * 64))[q];
    uint4 v1 = ((const uint4*)(F + (size_t)s0.y * 64))[q];
    uint4 v2 = ((const uint4*)(F + (size_t)s0.z * 64))[q];
    uint4 v3 = ((const uint4*)(F + (size_t)s0.w * 64))[q];
    ACC8(aA, v0) ACC8(aB, v1) ACC8(aA, v2) ACC8(aB, v3)
    e += 4;
  }
  for (; e < end; ++e) {
    uint4 v0 = ((const uint4*)(F + (size_t)csr[e] * 64))[q];
    ACC8(aA, v0)
  }
  float a[8];
  float iv = 1.0f / fmaxf((float)deg, 1.0f);
#pragma unroll
  for (int c = 0; c < 8; ++c) a[c] = (aA[c] + aB[c]) * iv;
  {
    uint4 z = ((const uint4*)(Z + (size_t)n * 64))[q];
    const float4* bp = (const float4*)(bias + q * 8);
    float4 b0 = bp[0], b1 = bp[1];
    a[0] = fmaxf(a[0] + b0.x + bflo(z.x), 0.f);
    a[1] = fmaxf(a[1] + b0.y + bfhi(z.x), 0.f);
    a[2] = fmaxf(a[2] + b0.z + bflo(z.y), 0.f);
    a[3] = fmaxf(a[3] + b0.w + bfhi(z.y), 0.f);
    a[4] = fmaxf(a[4] + b1.x + bflo(z.z), 0.f);
    a[5] = fmaxf(a[5] + b1.y + bfhi(z.z), 0.f);
    a[6] = fmaxf(a[6] + b1.z + bflo(z.w), 0.f);
    a[7] = fmaxf(a[7] + b1.w + bfhi(z.w), 0.f);
  }
  uint4 o;
  o.x = packbf2(a[0], a[1]); o.y = packbf2(a[2], a[3]);
  o.z = packbf2(a[4], a[5]); o.w = packbf2(a[6], a[7]);
  ((uint4*)(out + (size_t)n * 64))[q] = o;
}

// ---- gather-aggregate phase shared by k_fgemm1/k_fgemm: 4 lanes/row,
//      8 edges in flight, int4 index loads. Results in a0[16] (mean-scaled).
__device__ __forceinline__ void gather_row(
    const unsigned short* __restrict__ F, const int* __restrict__ csr,
    const int* __restrict__ cnt, int row, int qr, float* a0) {
#pragma unroll
  for (int c = 0; c < 16; ++c) a0[c] = 0.f;
  int deg = cnt[(size_t)row * CPAD];
  int degc = min(deg, MAXDEG);
  int beg = row * MAXDEG, end = beg + degc;
  int e = beg;
  for (; e + 8 <= end; e += 8) {  // 8 edges in flight
    int4 sa = *(const int4*)(csr + e);
    int4 sb = *(const int4*)(csr + e + 4);
    const uint4* r0 = (const uint4*)(F + (size_t)sa.x * 64) + qr * 2;
    const uint4* r1 = (const uint4*)(F + (size_t)sa.y * 64) + qr * 2;
    const uint4* r2 = (const uint4*)(F + (size_t)sa.z * 64) + qr * 2;
    const uint4* r3 = (const uint4*)(F + (size_t)sa.w * 64) + qr * 2;
    const uint4* r4 = (const uint4*)(F + (size_t)sb.x * 64) + qr * 2;
    const uint4* r5 = (const uint4*)(F + (size_t)sb.y * 64) + qr * 2;
    const uint4* r6 = (const uint4*)(F + (size_t)sb.z * 64) + qr * 2;
    const uint4* r7 = (const uint4*)(F + (size_t)sb.w * 64) + qr * 2;
    uint4 p0 = r0[0], p1 = r0[1], p2 = r1[0], p3 = r1[1];
    uint4 p4 = r2[0], p5 = r2[1], p6 = r3[0], p7 = r3[1];
    uint4 q0 = r4[0], q1 = r4[1], q2 = r5[0], q3 = r5[1];
    uint4 q4 = r6[0], q5 = r6[1], q6 = r7[0], q7 = r7[1];
    ACC16(a0, p0, p1) ACC16(a0, p2, p3)
    ACC16(a0, p4, p5) ACC16(a0, p6, p7)
    ACC16(a0, q0, q1) ACC16(a0, q2, q3)
    ACC16(a0, q4, q5) ACC16(a0, q6, q7)
  }
  if (e + 4 <= end) {
    int4 sa = *(const int4*)(csr + e);
    const uint4* r0 = (const uint4*)(F + (size_t)sa.x * 64) + qr * 2;
    const uint4* r1 = (const uint4*)(F + (size_t)sa.y * 64) + qr * 2;
    const uint4* r2 = (const uint4*)(F + (size_t)sa.z * 64) + qr * 2;
    const uint4* r3 = (const uint4*)(F + (size_t)sa.w * 64) + qr * 2;
    uint4 p0 = r0[0], p1 = r0[1], p2 = r1[0], p3 = r1[1];
    uint4 p4 = r2[0], p5 = r2[1], p6 = r3[0], p7 = r3[1];
    ACC16(a0, p0, p1) ACC16(a0, p2, p3)
    ACC16(a0, p4, p5) ACC16(a0, p6, p7)
    e += 4;
  }
  if (e + 2 <= end) {
    int s0 = csr[e], s1 = csr[e + 1];
    const uint4* r0 = (const uint4*)(F + (size_t)s0 * 64) + qr * 2;
    const uint4* r1 = (const uint4*)(F + (size_t)s1 * 64) + qr * 2;
    uint4 p0 = r0[0], p1 = r0[1], q0 = r1[0], q1 = r1[1];
    ACC16(a0, p0, p1) ACC16(a0, q0, q1)
    e += 2;
  }
  if (e < end) {
    const uint4* r0 = (const uint4*)(F + (size_t)csr[e] * 64) + qr * 2;
    uint4 p0 = r0[0], p1 = r0[1];
    ACC16(a0, p0, p1)
  }
  float iv = 1.0f / fmaxf((float)deg, 1.0f);
#pragma unroll
  for (int c = 0; c < 16; ++c) a0[c] *= iv;
}

// ---- layer-1 fused: h1 = relu(agg(x)@WL + Z), then B3=h1@c2wl, B4=h1@c2wr --
// h1 never touches global memory: relu'd tile is packed straight into a
// K=128 A-frag LDS buffer (identical staging formula to the old k_gemm).
__global__ __launch_bounds__(256, 4) void k_fgemm1(
    const unsigned short* __restrict__ F, const int* __restrict__ csr,
    const int* __restrict__ cnt,
    const unsigned short* __restrict__ Wp,   // pL1 (K=128 layout; WL = t 0,1)
    const unsigned short* __restrict__ ZZ,   // NN x 128 (x@wr + bias)
    const unsigned short* __restrict__ Wa,   // pL2a (c2_wl, K=128)
    const unsigned short* __restrict__ Wb,   // pL2b (c2_wr, K=128)
    unsigned short* __restrict__ OUTa,       // B3 = h1 @ c2_wl
    unsigned short* __restrict__ OUTb) {     // B4 = h1 @ c2_wr
  __shared__ __align__(16) char smem[64 * 66 * 4 + 64 * 128 * 2];
  __shared__ short skey[64];
  unsigned short* sA = (unsigned short*)smem;
  float* sC = (float*)smem;
  unsigned short* sA2 = (unsigned short*)(smem + 64 * 66 * 4);  // h1 K=128 frags
  const int tid = threadIdx.x;
  const int m0 = blockIdx.x * 64;

  sort_deg(cnt, m0, tid, skey);

  // ---- gather-aggregate into K=64 A-frags (rows permuted by degree)
  {
    int m = tid >> 2, qr = tid & 3;
    int row = m0 + (skey[m] & 63);
    float a0[16];
    if (row < NN) {
      gather_row(F, csr, cnt, row, qr, a0);
    } else {
#pragma unroll
      for (int c = 0; c < 16; ++c) a0[c] = 0.f;
    }
    int wv = m >> 4, mr = m & 15;
#pragma unroll
    for (int h = 0; h < 2; ++h) {
      int k8 = qr * 2 + h;  // 0..7, t = k8>>2 in {0,1}
      int t = k8 >> 2, kq = k8 & 3;
      uint4 o;
      o.x = packbf2(a0[h * 8 + 0], a0[h * 8 + 1]);
      o.y = packbf2(a0[h * 8 + 2], a0[h * 8 + 3]);
      o.z = packbf2(a0[h * 8 + 4], a0[h * 8 + 5]);
      o.w = packbf2(a0[h * 8 + 6], a0[h * 8 + 7]);
      ((uint4*)sA)[(wv * 2 + t) * 64 + kq * 16 + mr] = o;
    }
  }
  __syncthreads();

  const int w = tid >> 6, L = tid & 63;
  const bf16x8* Af = (const bf16x8*)sA;
  const bf16x8* Bf = (const bf16x8*)Wp;
  f32x4 acc[8];
#pragma unroll
  for (int i = 0; i < 8; ++i)
#pragma unroll
    for (int j = 0; j < 4; ++j) acc[i][j] = 0.f;
#pragma unroll
  for (int t = 0; t < 2; ++t) {  // WL rows of the K=128 pack
    bf16x8 afr = Af[(w * 2 + t) * 64 + L];
#pragma unroll
    for (int n0 = 0; n0 < 8; ++n0) {
      bf16x8 bfr = Bf[(n0 * 4 + t) * 64 + L];
      acc[n0] = __builtin_amdgcn_mfma_f32_16x16x32_bf16(afr, bfr, acc[n0], 0, 0, 0);
    }
  }

  // ---- epilogue 1: h1 = relu(acc + ZZ) packed into sA2 (K=128 A-frags)
  int rg = L >> 4, cl = L & 15;
#pragma unroll
  for (int half = 0; half < 2; ++half) {
    __syncthreads();
#pragma unroll
    for (int n0 = 0; n0 < 4; ++n0)
#pragma unroll
      for (int rr = 0; rr < 4; ++rr)
        sC[(w * 16 + rg * 4 + rr) * 66 + n0 * 16 + cl] = acc[half * 4 + n0][rr];
    __syncthreads();
#pragma unroll
    for (int it = 0; it < 2; ++it) {
      int c = tid + it * 256;
      int m = c >> 3, c8 = c & 7;
      int row = m0 + (skey[m] & 63);
      uint4 o = make_uint4(0, 0, 0, 0);
      if (row < NN) {
        uint4 z = ((const uint4*)(ZZ + (size_t)row * 128 + half * 64))[c8];
        float zb[8] = {bflo(z.x), bfhi(z.x), bflo(z.y), bfhi(z.y),
                       bflo(z.z), bfhi(z.z), bflo(z.w), bfhi(z.w)};
        float v[8];
#pragma unroll
        for (int j = 0; j < 8; ++j)
          v[j] = fmaxf(sC[m * 66 + c8 * 8 + j] + zb[j], 0.f);
        o.x = packbf2(v[0], v[1]); o.y = packbf2(v[2], v[3]);
        o.z = packbf2(v[4], v[5]); o.w = packbf2(v[6], v[7]);
      }
      int k8 = half * 8 + c8, t = k8 >> 2, kq = k8 & 3;
      int wv = m >> 4, mr = m & 15;
      ((uint4*)sA2)[(wv * 4 + t) * 64 + kq * 16 + mr] = o;
    }
  }
  __syncthreads();

  // ---- stage 2: B3 = h1@Wa, B4 = h1@Wb  (K=128, both in one t-sweep)
  const bf16x8* A2 = (const bf16x8*)sA2;
  const bf16x8* Ba = (const bf16x8*)Wa;
  const bf16x8* Bb = (const bf16x8*)Wb;
  f32x4 ca[4], cb[4];
#pragma unroll
  for (int i = 0; i < 4; ++i)
#pragma unroll
    for (int j = 0; j < 4; ++j) { ca[i][j] = 0.f; cb[i][j] = 0.f; }
#pragma unroll
  for (int t = 0; t < 4; ++t) {
    bf16x8 afr = A2[(w * 4 + t) * 64 + L];
#pragma unroll
    for (int n0 = 0; n0 < 4; ++n0) {
      ca[n0] = __builtin_amdgcn_mfma_f32_16x16x32_bf16(afr, Ba[(n0 * 4 + t) * 64 + L], ca[n0], 0, 0, 0);
      cb[n0] = __builtin_amdgcn_mfma_f32_16x16x32_bf16(afr, Bb[(n0 * 4 + t) * 64 + L], cb[n0], 0, 0, 0);
    }
  }
#pragma unroll
  for (int s = 0; s < 2; ++s) {
    unsigned short* OUT = s ? OUTb : OUTa;
    __syncthreads();
#pragma unroll
    for (int n0 = 0; n0 < 4; ++n0)
#pragma unroll
      for (int rr = 0; rr < 4; ++rr)
        sC[(w * 16 + rg * 4 + rr) * 66 + n0 * 16 + cl] =
            s ? cb[n0][rr] : ca[n0][rr];
    __syncthreads();
#pragma unroll
    for (int it = 0; it < 2; ++it) {
      int c = tid + it * 256;
      int m = c >> 3, c8 = c & 7;
      int row = m0 + (skey[m] & 63);
      if (row < NN) {
        float v[8];
#pragma unroll
        for (int j = 0; j < 8; ++j) v[j] = sC[m * 66 + c8 * 8 + j];
        uint4 o;
        o.x = packbf2(v[0], v[1]); o.y = packbf2(v[2], v[3]);
        o.z = packbf2(v[4], v[5]); o.w = packbf2(v[6], v[7]);
        ((uint4*)(OUT + (size_t)row * 64))[c8] = o;
      }
    }
  }
}

// ------------------------------------------- fused gather + MFMA GEMM -------
template <int NF>  // 4 (64 cols), K=128: gather half + own half
__global__ __launch_bounds__(256, 4) void k_fgemm(
    const unsigned short* __restrict__ F, const int* __restrict__ csr,
    const int* __restrict__ cnt,
    const unsigned short* __restrict__ Wp, const float* __restrict__ bias,
    unsigned short* __restrict__ OUT, int outStride) {
  __shared__ __align__(16) char smem[64 * 66 * 4];
  __shared__ short skey[64];
  unsigned short* sA = (unsigned short*)smem;
  float* sC = (float*)smem;
  const int tid = threadIdx.x;
  const int m0 = blockIdx.x * 64;

  sort_deg(cnt, m0, tid, skey);

  {
    int m = tid >> 2, qr = tid & 3;
    int row = m0 + (skey[m] & 63);
    float a0[16];
    if (row < NN) {
      gather_row(F, csr, cnt, row, qr, a0);
    } else {
#pragma unroll
      for (int c = 0; c < 16; ++c) a0[c] = 0.f;
    }
    int wv = m >> 4, mr = m & 15;
#pragma unroll
    for (int h = 0; h < 2; ++h) {
      int k8 = qr * 2 + h;
      int t = k8 >> 2, kq = k8 & 3;
      uint4 o;
      o.x = packbf2(a0[h * 8 + 0], a0[h * 8 + 1]);
      o.y = packbf2(a0[h * 8 + 2], a0[h * 8 + 3]);
      o.z = packbf2(a0[h * 8 + 4], a0[h * 8 + 5]);
      o.w = packbf2(a0[h * 8 + 6], a0[h * 8 + 7]);
      ((uint4*)sA)[(wv * 4 + t) * 64 + kq * 16 + mr] = o;
    }
  }
#pragma unroll
  for (int l = 0; l < 2; ++l) {
    int c = tid + l * 256;
    int m = c >> 3, j = c & 7;
    int row = m0 + (skey[m] & 63);
    uint4 v = make_uint4(0, 0, 0, 0);
    if (row < NN) v = ((const uint4*)(F + (size_t)row * 64))[j];
    int k8 = 8 + j, t = k8 >> 2, kq = k8 & 3;
    int wv = m >> 4, mr = m & 15;
    ((uint4*)sA)[(wv * 4 + t) * 64 + kq * 16 + mr] = v;
  }
  __syncthreads();

  const int w = tid >> 6, L = tid & 63;
  const bf16x8* Af = (const bf16x8*)sA;
  const bf16x8* Bf = (const bf16x8*)Wp;
  f32x4 acc[NF];
#pragma unroll
  for (int i = 0; i < NF; ++i)
#pragma unroll
    for (int j = 0; j < 4; ++j) acc[i][j] = 0.f;
#pragma unroll
  for (int t = 0; t < 4; ++t) {
    bf16x8 afr = Af[(w * 4 + t) * 64 + L];
#pragma unroll
    for (int n0 = 0; n0 < NF; ++n0) {
      bf16x8 bfr = Bf[(n0 * 4 + t) * 64 + L];
      acc[n0] = __builtin_amdgcn_mfma_f32_16x16x32_bf16(afr, bfr, acc[n0], 0, 0, 0);
    }
  }

  int rg = L >> 4, cl = L & 15;
#pragma unroll
  for (int half = 0; half < NF / 4; ++half) {
    __syncthreads();
#pragma unroll
    for (int n0 = 0; n0 < 4; ++n0)
#pragma unroll
      for (int rr = 0; rr < 4; ++rr)
        sC[(w * 16 + rg * 4 + rr) * 66 + n0 * 16 + cl] = acc[half * 4 + n0][rr];
    __syncthreads();
#pragma unroll
    for (int it = 0; it < 2; ++it) {
      int c = tid + it * 256;
      int m = c >> 3, c8 = c & 7;
      int row = m0 + (skey[m] & 63);
      if (row < NN) {
        float v[8];
#pragma unroll
        for (int j = 0; j < 8; ++j)
          v[j] = fmaxf(sC[m * 66 + c8 * 8 + j] + bias[half * 64 + c8 * 8 + j], 0.f);
        uint4 o;
        o.x = packbf2(v[0], v[1]); o.y = packbf2(v[2], v[3]);
        o.z = packbf2(v[4], v[5]); o.w = packbf2(v[6], v[7]);
        ((uint4*)(OUT + (size_t)row * outStride + half * 64))[c8] = o;
      }
    }
  }
}

// ----------------------------------------------- fused mean-pool + MLP ------
__global__ __launch_bounds__(64) void k_poolmlp(
    const unsigned short* __restrict__ H, const int* __restrict__ gstart,
    const float* __restrict__ w1, const float* __restrict__ b1,
    const float* __restrict__ w2, const float* __restrict__ b2,
    const float* __restrict__ w3, const float* __restrict__ b3,
    const float* __restrict__ w4, const float* __restrict__ b4,
    float* __restrict__ out) {
  __shared__ float sg[64], s1[64], s2[32], s3[32];
  int g = blockIdx.x, t = threadIdx.x;
  int beg = gstart[g], end = gstart[g + 1];
  float a0 = 0.f, a1 = 0.f, a2 = 0.f, a3 = 0.f;
  int n = beg;
  for (; n + 4 <= end; n += 4) {  // 4 rows in flight (coalesced 128B reads)
    a0 += bfs(H[(size_t)n * 64 + t]);
    a1 += bfs(H[(size_t)(n + 1) * 64 + t]);
    a2 += bfs(H[(size_t)(n + 2) * 64 + t]);
    a3 += bfs(H[(size_t)(n + 3) * 64 + t]);
  }
  for (; n < end; ++n) a0 += bfs(H[(size_t)n * 64 + t]);
  float cnt = fmaxf((float)(end - beg), 1.0f);
  sg[t] = ((a0 + a1) + (a2 + a3)) / cnt;
  __syncthreads();
  float acc = b1[t];
  for (int k = 0; k < 64; ++k) acc += sg[k] * w1[k * 64 + t];
  s1[t] = fmaxf(acc, 0.0f);
  __syncthreads();
  if (t < 32) {
    acc = b2[t];
    for (int k = 0; k < 64; ++k) acc += s1[k] * w2[k * 32 + t];
    s2[t] = fmaxf(acc, 0.0f);
  }
  __syncthreads();
  if (t < 32) {
    acc = b3[t];
    for (int k = 0; k < 32; ++k) acc += s2[k] * w3[k * 32 + t];
    s3[t] = fmaxf(acc, 0.0f);
  }
  __syncthreads();
  if (t == 0) {
    acc = b4[0];
    for (int k = 0; k < 32; ++k) acc += s3[k] * w4[k];
    out[g] = acc;
  }
}

// ---------------------------------------------------------------- launch ----
extern "C" void kernel_launch(void* const* d_in, const int* in_sizes, int n_in,
                              void* d_out, int out_size, void* d_ws,
                              size_t ws_size, hipStream_t stream) {
  const float* x     = (const float*)d_in[0];
  const int*   ei    = (const int*)d_in[1];
  const int*   batch = (const int*)d_in[2];
  const int* src = ei;
  const int* dst = ei + NE;

  const float* c1_wl = (const float*)d_in[3];
  const float* c1_bl = (const float*)d_in[4];
  const float* c1_wr = (const float*)d_in[5];
  const float* c2_wl = (const float*)d_in[6];
  const float* c2_bl = (const float*)d_in[7];
  const float* c2_wr = (const float*)d_in[8];
  const float* c3_wl = (const float*)d_in[9];
  const float* c3_bl = (const float*)d_in[10];
  const float* c3_wr = (const float*)d_in[11];
  const float* c4_wl = (const float*)d_in[12];
  const float* c4_bl = (const float*)d_in[13];
  const float* c4_wr = (const float*)d_in[14];
  const float* l1w = (const float*)d_in[15];
  const float* l1b = (const float*)d_in[16];
  const float* l2w = (const float*)d_in[17];
  const float* l2b = (const float*)d_in[18];
  const float* l3w = (const float*)d_in[19];
  const float* l3b = (const float*)d_in[20];
  const float* l4w = (const float*)d_in[21];
  const float* l4b = (const float*)d_in[22];

  // ---- workspace carve-up
  char* wsb = (char*)d_ws;
  unsigned short* xb  = (unsigned short*)wsb;
  unsigned short* B1  = xb + (size_t)NN * 64;    // h2 / h4
  unsigned short* B3  = B1 + (size_t)NN * 64;    // U / h3
  unsigned short* B4  = B3 + (size_t)NN * 64;    // V
  unsigned short* ZZ  = B4 + (size_t)NN * 64;    // x@wr + bias (NN x 128)
  unsigned short* pL1  = ZZ + (size_t)NN * 128;  // 128x128 pack
  unsigned short* pL2a = pL1 + 128 * 128;
  unsigned short* pL2b = pL2a + 128 * 64;
  unsigned short* pL3  = pL2b + 128 * 64;
  unsigned short* pL4  = pL3 + 128 * 64;
  unsigned short* pLZ  = pL4 + 128 * 64;         // 64x128 pack (Z-gemm)
  int* cnt    = (int*)(pLZ + 64 * 128);          // NN*CPAD
  int* gstart = cnt + (size_t)NN * CPAD;         // NG+1
  int* csr    = gstart + NG + 1 + 2;             // NN*MAXDEG (padded CSR)

  const int gN8 = NN * 8 / 256;       // 3125
  const int gM  = (NN + 63) / 64;     // 1563

  hipMemsetAsync(cnt, 0, (size_t)NN * CPAD * 4, stream);

  // ---- Z-gemm weight pack (must precede k_setup which reads it)
  k_prepz<<<32, 256, 0, stream>>>(c1_wr, pLZ);

  // ---- merged setup: count+fill (10 of 13 groups) + Z/bnd/prep (3 of 13);
  //      Z-gemm now also emits xb (cvt pass deleted)
  k_setup<<<GB_SETUP, 256, 0, stream>>>(src, dst, cnt, csr, x, xb, batch,
                                        gstart, pLZ, c1_bl, ZZ,
                                        c1_wl, c1_wr, c2_wl, c2_wr,
                                        c3_wl, c3_wr, c4_wl, c4_wr,
                                        pL1, pL2a, pL2b, pL3, pL4);

  // ---- layer 1+2a (fused): h1 = relu(agg(x)@WL + ZZ) kept in LDS;
  //      B3 = h1@c2wl, B4 = h1@c2wr written directly (h1 never hits HBM)
  k_fgemm1<<<gM, 256, 0, stream>>>(xb, csr, cnt, pL1, ZZ, pL2a, pL2b, B3, B4);

  // ---- layer 2b: B1(h2) = relu(agg(B3) + b + B4)
  k_gather<<<gN8, 256, 0, stream>>>(B3, csr, cnt, c2_bl, B4, B1);

  // ---- layer 3 (fused): B3(h3) = relu([agg(h2)|h2] @ pL3 + c3_bl)
  k_fgemm<4><<<gM, 256, 0, stream>>>(B1, csr, cnt, pL3, c3_bl, B3, 64);

  // ---- layer 4 (fused): B1(h4) = relu([agg(h3)|h3] @ pL4 + c4_bl)
  k_fgemm<4><<<gM, 256, 0, stream>>>(B3, csr, cnt, pL4, c4_bl, B1, 64);

  // ---- fused pool + MLP
  k_poolmlp<<<NG, 64, 0, stream>>>(B1, gstart, l1w, l1b, l2w, l2b,
                                   l3w, l3b, l4w, l4b, (float*)d_out);
}

// Round 7
// 347.713 us; speedup vs baseline: 1.1246x; 1.1246x over previous
//
#include <hip/hip_runtime.h>

#define NN 100000
#define NE 1600000
#define NG 1024
#define CPAD 4     // counter stride (ints). R8/R9: atomic-throughput-bound either way
#define MAXDEG 64  // padded CSR row; Poisson(16) -> P(deg>=64) ~ 1e-19 per node

// merged-setup grid, interleaved in GROUPS OF 8 so count blocks cover all
// 8 XCDs (R4: atomics confined to <4 XCDs serialize). 1:1 group alternation
// (R6: denser atomic packing regresses — compute groups are dilution).
#define GB_COUNT 6250   // NE/256 count blocks, 1 edge/thread
#define GB_Z     1563   // ceil(NN/64) Z-gemm blocks
#define GB_CVT   3125   // NN*64/8/256  (kept: cheap dilution material, R6 lesson)
#define GB_BND   5
#define GB_PREP  320    // 5 matrices x 64 blocks
#define GB_ODD   (GB_Z + GB_CVT + GB_BND + GB_PREP)  // 5013
#define GB_SETUP 12504  // g=0..1562; 782 count groups (6256 slots), 781 compute groups

typedef __attribute__((ext_vector_type(8))) short bf16x8;
typedef __attribute__((ext_vector_type(4))) float f32x4;

__device__ __forceinline__ unsigned f2bf1(float f) {
  union { float f; unsigned u; } v; v.f = f;
  return (v.u + 0x7fffu + ((v.u >> 16) & 1u)) >> 16;  // RNE
}
__device__ __forceinline__ unsigned packbf2(float a, float b) {
  return f2bf1(a) | (f2bf1(b) << 16);
}
__device__ __forceinline__ float bflo(unsigned u) {
  union { unsigned u; float f; } v; v.u = u << 16; return v.f;
}
__device__ __forceinline__ float bfhi(unsigned u) {
  union { unsigned u; float f; } v; v.u = u & 0xffff0000u; return v.f;
}
__device__ __forceinline__ float bfs(unsigned short s) {
  union { unsigned u; float f; } v; v.u = ((unsigned)s) << 16; return v.f;
}

// accumulate 16 bf16 channels (two uint4 = 32B) into A[16]
#define ACC16(A, P0, P1)                                              \
  A[0] += bflo(P0.x); A[1] += bfhi(P0.x);                             \
  A[2] += bflo(P0.y); A[3] += bfhi(P0.y);                             \
  A[4] += bflo(P0.z); A[5] += bfhi(P0.z);                             \
  A[6] += bflo(P0.w); A[7] += bfhi(P0.w);                             \
  A[8] += bflo(P1.x); A[9] += bfhi(P1.x);                             \
  A[10] += bflo(P1.y); A[11] += bfhi(P1.y);                           \
  A[12] += bflo(P1.z); A[13] += bfhi(P1.z);                           \
  A[14] += bflo(P1.w); A[15] += bfhi(P1.w);

// accumulate 8 bf16 channels (one uint4 = 16B) into A[8]
#define ACC8(A, V)                                                    \
  A[0] += bflo(V.x); A[1] += bfhi(V.x);                               \
  A[2] += bflo(V.y); A[3] += bfhi(V.y);                               \
  A[4] += bflo(V.z); A[5] += bfhi(V.z);                               \
  A[6] += bflo(V.w); A[7] += bfhi(V.w);

// ---- pre-pack c1_wr (K=64,N=128) B-frags for the Z-gemm + zero cnt ---------
// b<32: weight pack; b>=32: zero cnt (folds the hipMemsetAsync dispatch away)
__global__ __launch_bounds__(256) void k_prepz(const float* __restrict__ c1wr,
                                               unsigned short* __restrict__ pLZ,
                                               int* __restrict__ cnt) {
  int b = blockIdx.x;
  if (b >= 32) {  // ---- zero cnt: NN*CPAD ints = 100000 int4 stores
    int i = (b - 32) * 256 + threadIdx.x;
    if (i < NN * CPAD / 4) ((int4*)cnt)[i] = make_int4(0, 0, 0, 0);
    return;
  }
  int e = b * 256 + threadIdx.x;  // 64*128 = 8192
  if (e >= 64 * 128) return;
  int k = e >> 7, n = e & 127;
  int t = k >> 5, kq = (k >> 3) & 3, j = k & 7;
  int n0 = n >> 4, nl = n & 15;
  pLZ[((((n0 * 2 + t) * 64) + (kq * 16 + nl)) << 3) + j] =
      (unsigned short)f2bf1(c1wr[k * 128 + n]);
}

// ---------------------------------------------------------- merged setup ----
// count blocks: one atomic per edge does BOTH count and CSR slot assignment
// (padded csr rows -> no scan/fill dependency).
__global__ __launch_bounds__(256) void k_setup(
    const int* __restrict__ src, const int* __restrict__ dst,
    int* __restrict__ cnt, int* __restrict__ csr,
    const float* __restrict__ X, unsigned short* __restrict__ Xb,
    const int* __restrict__ batch, int* __restrict__ gstart,
    const unsigned short* __restrict__ pLZ, const float* __restrict__ c1bl,
    unsigned short* __restrict__ ZZ,
    const float* __restrict__ c1wl, const float* __restrict__ c1wr,
    const float* __restrict__ c2wl, const float* __restrict__ c2wr,
    const float* __restrict__ c3wl, const float* __restrict__ c3wr,
    const float* __restrict__ c4wl, const float* __restrict__ c4wr,
    unsigned short* __restrict__ pL1, unsigned short* __restrict__ pL2a,
    unsigned short* __restrict__ pL2b, unsigned short* __restrict__ pL3,
    unsigned short* __restrict__ pL4) {
  __shared__ __align__(16) char smem[64 * 66 * 4];  // Z-gemm sA/sC
  int b = blockIdx.x, tid = threadIdx.x;
  int g = b >> 3, i = b & 7;  // i spans all 8 XCDs within each group

  if ((g & 1) == 0) {  // ---- count + fill (atomic-bound; all XCDs issuing)
    int cb = (g >> 1) * 8 + i;
    if (cb >= GB_COUNT) return;
    int e = cb * 256 + tid;
    int d = dst[e];
    int s = src[e];
    int r = atomicAdd(&cnt[(size_t)d * CPAD], 1);
    if (r < MAXDEG) csr[d * MAXDEG + r] = s;
    return;
  }
  int ob = (g >> 1) * 8 + i;  // compute index
  if (ob >= GB_ODD) return;

  if (ob < GB_Z) {  // ---- Z-gemm: ZZ = x @ c1_wr + c1_bl  (bf16, no relu)
    unsigned short* sA = (unsigned short*)smem;
    float* sC = (float*)smem;
    const int m0 = ob * 64;
    // stage A (64 rows x 64 k, fp32 -> bf16 A-frags, K=64 layout)
#pragma unroll
    for (int l = 0; l < 2; ++l) {
      int c = tid + l * 256;  // 512 chunks
      int m = c >> 3, k8 = c & 7;
      int row = m0 + m;
      uint4 o = make_uint4(0, 0, 0, 0);
      if (row < NN) {
        const float4* xp = (const float4*)(X + (size_t)row * 64 + k8 * 8);
        float4 p0 = xp[0], p1 = xp[1];
        o.x = packbf2(p0.x, p0.y); o.y = packbf2(p0.z, p0.w);
        o.z = packbf2(p1.x, p1.y); o.w = packbf2(p1.z, p1.w);
      }
      int wv = m >> 4, mr = m & 15, t = k8 >> 2, kq = k8 & 3;
      ((uint4*)sA)[(wv * 2 + t) * 64 + kq * 16 + mr] = o;
    }
    __syncthreads();
    const int w = tid >> 6, L = tid & 63;
    const bf16x8* Af = (const bf16x8*)sA;
    const bf16x8* Bf = (const bf16x8*)pLZ;
    f32x4 acc[8];
#pragma unroll
    for (int i2 = 0; i2 < 8; ++i2)
#pragma unroll
      for (int j = 0; j < 4; ++j) acc[i2][j] = 0.f;
#pragma unroll
    for (int t = 0; t < 2; ++t) {
      bf16x8 afr = Af[(w * 2 + t) * 64 + L];
#pragma unroll
      for (int n0 = 0; n0 < 8; ++n0) {
        bf16x8 bfr = Bf[(n0 * 2 + t) * 64 + L];
        acc[n0] = __builtin_amdgcn_mfma_f32_16x16x32_bf16(afr, bfr, acc[n0], 0, 0, 0);
      }
    }
    int rg = L >> 4, cl = L & 15;
#pragma unroll
    for (int half = 0; half < 2; ++half) {
      __syncthreads();
#pragma unroll
      for (int n0 = 0; n0 < 4; ++n0)
#pragma unroll
        for (int rr = 0; rr < 4; ++rr)
          sC[(w * 16 + rg * 4 + rr) * 66 + n0 * 16 + cl] = acc[half * 4 + n0][rr];
      __syncthreads();
#pragma unroll
      for (int it = 0; it < 2; ++it) {
        int c = tid + it * 256;
        int m = c >> 3, c8 = c & 7;
        int row = m0 + m;
        if (row < NN) {
          float v[8];
#pragma unroll
          for (int j = 0; j < 8; ++j)
            v[j] = sC[m * 66 + c8 * 8 + j] + c1bl[half * 64 + c8 * 8 + j];
          uint4 o;
          o.x = packbf2(v[0], v[1]); o.y = packbf2(v[2], v[3]);
          o.z = packbf2(v[4], v[5]); o.w = packbf2(v[6], v[7]);
          ((uint4*)(ZZ + (size_t)row * 128 + half * 64))[c8] = o;
        }
      }
    }
    return;
  }
  ob -= GB_Z;
  if (ob < GB_CVT) {  // ---- x fp32 -> bf16
    int i2 = ob * 256 + tid;
    const float4* p = (const float4*)X + (size_t)i2 * 2;
    float4 a = p[0], c = p[1];
    uint4 o;
    o.x = packbf2(a.x, a.y); o.y = packbf2(a.z, a.w);
    o.z = packbf2(c.x, c.y); o.w = packbf2(c.z, c.w);
    ((uint4*)Xb)[i2] = o;
    return;
  }
  ob -= GB_CVT;
  if (ob < GB_BND) {  // ---- graph bounds (sorted batch)
    int gg = ob * 256 + tid;
    if (gg > NG) return;
    int lo = 0, hi = NN;
    while (lo < hi) {
      int mid = (lo + hi) >> 1;
      if (batch[mid] < gg) lo = mid + 1; else hi = mid;
    }
    gstart[gg] = lo;
    return;
  }
  ob -= GB_BND;
  if (ob < GB_PREP) {  // ---- pack conv weights (K=128 B-frag layout)
    int yb = ob >> 6, xb2 = ob & 63;
    const float *WL, *WR; unsigned short* dstp; int N;
    if (yb == 0)      { WL = c1wl; WR = c1wr;           dstp = pL1;  N = 128; }
    else if (yb == 1) { WL = c2wl; WR = c2wl + 64 * 64; dstp = pL2a; N = 64; }
    else if (yb == 2) { WL = c2wr; WR = c2wr + 64 * 64; dstp = pL2b; N = 64; }
    else if (yb == 3) { WL = c3wl; WR = c3wr;           dstp = pL3;  N = 64; }
    else              { WL = c4wl; WR = c4wr;           dstp = pL4;  N = 64; }
    int e = xb2 * 256 + tid;
    if (e >= 128 * N) return;
    int k = e / N, n = e - k * N;
    float w = (k < 64) ? WL[k * N + n] : WR[(k - 64) * N + n];
    int t = k >> 5, kq = (k >> 3) & 3, j = k & 7;
    int n0 = n >> 4, nl = n & 15;
    dstp[((((n0 * 4 + t) * 64) + (kq * 16 + nl)) << 3) + j] =
        (unsigned short)f2bf1(w);
  }
}

// ---------------------------- gather (layer-2 epilogue: relu(agg+b+Z)) ------
__global__ __launch_bounds__(256) void k_gather(
    const unsigned short* __restrict__ F, const int* __restrict__ csr,
    const int* __restrict__ cnt, const float* __restrict__ bias,
    const unsigned short* __restrict__ Z, unsigned short* __restrict__ out) {
  int idx = blockIdx.x * 256 + threadIdx.x;  // grid = NN*8 threads
  int n = idx >> 3, q = idx & 7;
  int deg = cnt[(size_t)n * CPAD];
  int degc = min(deg, MAXDEG);
  int beg = n * MAXDEG, end = beg + degc;
  float aA[8], aB[8];
#pragma unroll
  for (int c = 0; c < 8; ++c) { aA[c] = 0.f; aB[c] = 0.f; }
  int e = beg;
  for (; e + 8 <= end; e += 8) {  // 8 edges in flight, int4 index loads
    int4 s0 = *(const int4*)(csr + e);
    int4 s1 = *(const int4*)(csr + e + 4);
    uint4 v0 = ((const uint4*)(F + (size_t)s0.x * 64))[q];
    uint4 v1 = ((const uint4*)(F + (size_t)s0.y * 64))[q];
    uint4 v2 = ((const uint4*)(F + (size_t)s0.z * 64))[q];
    uint4 v3 = ((const uint4*)(F + (size_t)s0.w * 64))[q];
    uint4 v4 = ((const uint4*)(F + (size_t)s1.x * 64))[q];
    uint4 v5 = ((const uint4*)(F + (size_t)s1.y * 64))[q];
    uint4 v6 = ((const uint4*)(F + (size_t)s1.z * 64))[q];
    uint4 v7 = ((const uint4*)(F + (size_t)s1.w * 64))[q];
    ACC8(aA, v0) ACC8(aB, v1) ACC8(aA, v2) ACC8(aB, v3)
    ACC8(aA, v4) ACC8(aB, v5) ACC8(aA, v6) ACC8(aB, v7)
  }
  if (e + 4 <= end) {
    int4 s0 = *(const int4*)(csr + e);
    uint4 v0 = ((const uint4*)(F + (size_t)s0.x * 64))[q];
    uint4 v1 = ((const uint4*)(F + (size_t)s0.y * 64))[q];
    uint4 v2 = ((const uint4*)(F + (size_t)s0.z * 64))[q];
    uint4 v3 = ((const uint4*)(F + (size_t)s0.w * 64))[q];
    ACC8(aA, v0) ACC8(aB, v1) ACC8(aA, v2) ACC8(aB, v3)
    e += 4;
  }
  for (; e < end; ++e) {
    uint4 v0 = ((const uint4*)(F + (size_t)csr[e] * 64))[q];
    ACC8(aA, v0)
  }
  float a[8];
  float iv = 1.0f / fmaxf((float)deg, 1.0f);
#pragma unroll
  for (int c = 0; c < 8; ++c) a[c] = (aA[c] + aB[c]) * iv;
  {
    uint4 z = ((const uint4*)(Z + (size_t)n * 64))[q];
    const float4* bp = (const float4*)(bias + q * 8);
    float4 b0 = bp[0], b1 = bp[1];
    a[0] = fmaxf(a[0] + b0.x + bflo(z.x), 0.f);
    a[1] = fmaxf(a[1] + b0.y + bfhi(z.x), 0.f);
    a[2] = fmaxf(a[2] + b0.z + bflo(z.y), 0.f);
    a[3] = fmaxf(a[3] + b0.w + bfhi(z.y), 0.f);
    a[4] = fmaxf(a[4] + b1.x + bflo(z.z), 0.f);
    a[5] = fmaxf(a[5] + b1.y + bfhi(z.z), 0.f);
    a[6] = fmaxf(a[6] + b1.z + bflo(z.w), 0.f);
    a[7] = fmaxf(a[7] + b1.w + bfhi(z.w), 0.f);
  }
  uint4 o;
  o.x = packbf2(a[0], a[1]); o.y = packbf2(a[2], a[3]);
  o.z = packbf2(a[4], a[5]); o.w = packbf2(a[6], a[7]);
  ((uint4*)(out + (size_t)n * 64))[q] = o;
}

// ---- gather-aggregate phase shared by k_fgemm1/k_fgemm: 4 lanes/row,
//      8 edges in flight, int4 index loads. Results in a0[16] (mean-scaled).
__device__ __forceinline__ void gather_row(
    const unsigned short* __restrict__ F, const int* __restrict__ csr,
    const int* __restrict__ cnt, int row, int qr, float* a0) {
#pragma unroll
  for (int c = 0; c < 16; ++c) a0[c] = 0.f;
  int deg = cnt[(size_t)row * CPAD];
  int degc = min(deg, MAXDEG);
  int beg = row * MAXDEG, end = beg + degc;
  int e = beg;
  for (; e + 8 <= end; e += 8) {  // 8 edges in flight
    int4 sa = *(const int4*)(csr + e);
    int4 sb = *(const int4*)(csr + e + 4);
    const uint4* r0 = (const uint4*)(F + (size_t)sa.x * 64) + qr * 2;
    const uint4* r1 = (const uint4*)(F + (size_t)sa.y * 64) + qr * 2;
    const uint4* r2 = (const uint4*)(F + (size_t)sa.z * 64) + qr * 2;
    const uint4* r3 = (const uint4*)(F + (size_t)sa.w * 64) + qr * 2;
    const uint4* r4 = (const uint4*)(F + (size_t)sb.x * 64) + qr * 2;
    const uint4* r5 = (const uint4*)(F + (size_t)sb.y * 64) + qr * 2;
    const uint4* r6 = (const uint4*)(F + (size_t)sb.z * 64) + qr * 2;
    const uint4* r7 = (const uint4*)(F + (size_t)sb.w * 64) + qr * 2;
    uint4 p0 = r0[0], p1 = r0[1], p2 = r1[0], p3 = r1[1];
    uint4 p4 = r2[0], p5 = r2[1], p6 = r3[0], p7 = r3[1];
    uint4 q0 = r4[0], q1 = r4[1], q2 = r5[0], q3 = r5[1];
    uint4 q4 = r6[0], q5 = r6[1], q6 = r7[0], q7 = r7[1];
    ACC16(a0, p0, p1) ACC16(a0, p2, p3)
    ACC16(a0, p4, p5) ACC16(a0, p6, p7)
    ACC16(a0, q0, q1) ACC16(a0, q2, q3)
    ACC16(a0, q4, q5) ACC16(a0, q6, q7)
  }
  if (e + 4 <= end) {
    int4 sa = *(const int4*)(csr + e);
    const uint4* r0 = (const uint4*)(F + (size_t)sa.x * 64) + qr * 2;
    const uint4* r1 = (const uint4*)(F + (size_t)sa.y * 64) + qr * 2;
    const uint4* r2 = (const uint4*)(F + (size_t)sa.z * 64) + qr * 2;
    const uint4* r3 = (const uint4*)(F + (size_t)sa.w * 64) + qr * 2;
    uint4 p0 = r0[0], p1 = r0[1], p2 = r1[0], p3 = r1[1];
    uint4 p4 = r2[0], p5 = r2[1], p6 = r3[0], p7 = r3[1];
    ACC16(a0, p0, p1) ACC16(a0, p2, p3)
    ACC16(a0, p4, p5) ACC16(a0, p6, p7)
    e += 4;
  }
  if (e + 2 <= end) {
    int s0 = csr[e], s1 = csr[e + 1];
    const uint4* r0 = (const uint4*)(F + (size_t)s0 * 64) + qr * 2;
    const uint4* r1 = (const uint4*)(F + (size_t)s1 * 64) + qr * 2;
    uint4 p0 = r0[0], p1 = r0[1], q0 = r1[0], q1 = r1[1];
    ACC16(a0, p0, p1) ACC16(a0, q0, q1)
    e += 2;
  }
  if (e < end) {
    const uint4* r0 = (const uint4*)(F + (size_t)csr[e] * 64) + qr * 2;
    uint4 p0 = r0[0], p1 = r0[1];
    ACC16(a0, p0, p1)
  }
  float iv = 1.0f / fmaxf((float)deg, 1.0f);
#pragma unroll
  for (int c = 0; c < 16; ++c) a0[c] *= iv;
}

// ---- layer-1 fused: h1 = relu(agg(x)@WL + Z), then B3=h1@c2wl, B4=h1@c2wr --
// h1 never touches global memory: relu'd tile is packed straight into a
// K=128 A-frag LDS buffer (identical staging formula to the old k_gemm).
__global__ __launch_bounds__(256, 4) void k_fgemm1(
    const unsigned short* __restrict__ F, const int* __restrict__ csr,
    const int* __restrict__ cnt,
    const unsigned short* __restrict__ Wp,   // pL1 (K=128 layout; WL = t 0,1)
    const unsigned short* __restrict__ ZZ,   // NN x 128 (x@wr + bias)
    const unsigned short* __restrict__ Wa,   // pL2a (c2_wl, K=128)
    const unsigned short* __restrict__ Wb,   // pL2b (c2_wr, K=128)
    unsigned short* __restrict__ OUTa,       // B3 = h1 @ c2_wl
    unsigned short* __restrict__ OUTb) {     // B4 = h1 @ c2_wr
  __shared__ __align__(16) char smem[64 * 66 * 4 + 64 * 128 * 2];
  unsigned short* sA = (unsigned short*)smem;
  float* sC = (float*)smem;
  unsigned short* sA2 = (unsigned short*)(smem + 64 * 66 * 4);  // h1 K=128 frags
  const int tid = threadIdx.x;
  const int m0 = blockIdx.x * 64;

  // ---- gather-aggregate into K=64 A-frags
  {
    int m = tid >> 2, qr = tid & 3;
    int row = m0 + m;
    float a0[16];
    if (row < NN) {
      gather_row(F, csr, cnt, row, qr, a0);
    } else {
#pragma unroll
      for (int c = 0; c < 16; ++c) a0[c] = 0.f;
    }
    int wv = m >> 4, mr = m & 15;
#pragma unroll
    for (int h = 0; h < 2; ++h) {
      int k8 = qr * 2 + h;  // 0..7, t = k8>>2 in {0,1}
      int t = k8 >> 2, kq = k8 & 3;
      uint4 o;
      o.x = packbf2(a0[h * 8 + 0], a0[h * 8 + 1]);
      o.y = packbf2(a0[h * 8 + 2], a0[h * 8 + 3]);
      o.z = packbf2(a0[h * 8 + 4], a0[h * 8 + 5]);
      o.w = packbf2(a0[h * 8 + 6], a0[h * 8 + 7]);
      ((uint4*)sA)[(wv * 2 + t) * 64 + kq * 16 + mr] = o;
    }
  }
  __syncthreads();

  const int w = tid >> 6, L = tid & 63;
  const bf16x8* Af = (const bf16x8*)sA;
  const bf16x8* Bf = (const bf16x8*)Wp;
  f32x4 acc[8];
#pragma unroll
  for (int i = 0; i < 8; ++i)
#pragma unroll
    for (int j = 0; j < 4; ++j) acc[i][j] = 0.f;
#pragma unroll
  for (int t = 0; t < 2; ++t) {  // WL rows of the K=128 pack
    bf16x8 afr = Af[(w * 2 + t) * 64 + L];
#pragma unroll
    for (int n0 = 0; n0 < 8; ++n0) {
      bf16x8 bfr = Bf[(n0 * 4 + t) * 64 + L];
      acc[n0] = __builtin_amdgcn_mfma_f32_16x16x32_bf16(afr, bfr, acc[n0], 0, 0, 0);
    }
  }

  // ---- epilogue 1: h1 = relu(acc + ZZ) packed into sA2 (K=128 A-frags)
  int rg = L >> 4, cl = L & 15;
#pragma unroll
  for (int half = 0; half < 2; ++half) {
    __syncthreads();
#pragma unroll
    for (int n0 = 0; n0 < 4; ++n0)
#pragma unroll
      for (int rr = 0; rr < 4; ++rr)
        sC[(w * 16 + rg * 4 + rr) * 66 + n0 * 16 + cl] = acc[half * 4 + n0][rr];
    __syncthreads();
#pragma unroll
    for (int it = 0; it < 2; ++it) {
      int c = tid + it * 256;
      int m = c >> 3, c8 = c & 7;
      int row = m0 + m;
      uint4 o = make_uint4(0, 0, 0, 0);
      if (row < NN) {
        uint4 z = ((const uint4*)(ZZ + (size_t)row * 128 + half * 64))[c8];
        float zb[8] = {bflo(z.x), bfhi(z.x), bflo(z.y), bfhi(z.y),
                       bflo(z.z), bfhi(z.z), bflo(z.w), bfhi(z.w)};
        float v[8];
#pragma unroll
        for (int j = 0; j < 8; ++j)
          v[j] = fmaxf(sC[m * 66 + c8 * 8 + j] + zb[j], 0.f);
        o.x = packbf2(v[0], v[1]); o.y = packbf2(v[2], v[3]);
        o.z = packbf2(v[4], v[5]); o.w = packbf2(v[6], v[7]);
      }
      int k8 = half * 8 + c8, t = k8 >> 2, kq = k8 & 3;
      int wv = m >> 4, mr = m & 15;
      ((uint4*)sA2)[(wv * 4 + t) * 64 + kq * 16 + mr] = o;
    }
  }
  __syncthreads();

  // ---- stage 2: B3 = h1@Wa, B4 = h1@Wb  (K=128, both in one t-sweep)
  const bf16x8* A2 = (const bf16x8*)sA2;
  const bf16x8* Ba = (const bf16x8*)Wa;
  const bf16x8* Bb = (const bf16x8*)Wb;
  f32x4 ca[4], cb[4];
#pragma unroll
  for (int i = 0; i < 4; ++i)
#pragma unroll
    for (int j = 0; j < 4; ++j) { ca[i][j] = 0.f; cb[i][j] = 0.f; }
#pragma unroll
  for (int t = 0; t < 4; ++t) {
    bf16x8 afr = A2[(w * 4 + t) * 64 + L];
#pragma unroll
    for (int n0 = 0; n0 < 4; ++n0) {
      ca[n0] = __builtin_amdgcn_mfma_f32_16x16x32_bf16(afr, Ba[(n0 * 4 + t) * 64 + L], ca[n0], 0, 0, 0);
      cb[n0] = __builtin_amdgcn_mfma_f32_16x16x32_bf16(afr, Bb[(n0 * 4 + t) * 64 + L], cb[n0], 0, 0, 0);
    }
  }
#pragma unroll
  for (int s = 0; s < 2; ++s) {
    unsigned short* OUT = s ? OUTb : OUTa;
    __syncthreads();
#pragma unroll
    for (int n0 = 0; n0 < 4; ++n0)
#pragma unroll
      for (int rr = 0; rr < 4; ++rr)
        sC[(w * 16 + rg * 4 + rr) * 66 + n0 * 16 + cl] =
            s ? cb[n0][rr] : ca[n0][rr];
    __syncthreads();
#pragma unroll
    for (int it = 0; it < 2; ++it) {
      int c = tid + it * 256;
      int m = c >> 3, c8 = c & 7;
      int row = m0 + m;
      if (row < NN) {
        float v[8];
#pragma unroll
        for (int j = 0; j < 8; ++j) v[j] = sC[m * 66 + c8 * 8 + j];
        uint4 o;
        o.x = packbf2(v[0], v[1]); o.y = packbf2(v[2], v[3]);
        o.z = packbf2(v[4], v[5]); o.w = packbf2(v[6], v[7]);
        ((uint4*)(OUT + (size_t)row * 64))[c8] = o;
      }
    }
  }
}

// ------------------------------------------- fused gather + MFMA GEMM -------
template <int NF>  // 4 (64 cols), K=128: gather half + own half
__global__ __launch_bounds__(256, 4) void k_fgemm(
    const unsigned short* __restrict__ F, const int* __restrict__ csr,
    const int* __restrict__ cnt,
    const unsigned short* __restrict__ Wp, const float* __restrict__ bias,
    unsigned short* __restrict__ OUT, int outStride) {
  __shared__ __align__(16) char smem[64 * 66 * 4];
  unsigned short* sA = (unsigned short*)smem;
  float* sC = (float*)smem;
  const int tid = threadIdx.x;
  const int m0 = blockIdx.x * 64;

  {
    int m = tid >> 2, qr = tid & 3;
    int row = m0 + m;
    float a0[16];
    if (row < NN) {
      gather_row(F, csr, cnt, row, qr, a0);
    } else {
#pragma unroll
      for (int c = 0; c < 16; ++c) a0[c] = 0.f;
    }
    int wv = m >> 4, mr = m & 15;
#pragma unroll
    for (int h = 0; h < 2; ++h) {
      int k8 = qr * 2 + h;
      int t = k8 >> 2, kq = k8 & 3;
      uint4 o;
      o.x = packbf2(a0[h * 8 + 0], a0[h * 8 + 1]);
      o.y = packbf2(a0[h * 8 + 2], a0[h * 8 + 3]);
      o.z = packbf2(a0[h * 8 + 4], a0[h * 8 + 5]);
      o.w = packbf2(a0[h * 8 + 6], a0[h * 8 + 7]);
      ((uint4*)sA)[(wv * 4 + t) * 64 + kq * 16 + mr] = o;
    }
  }
#pragma unroll
  for (int l = 0; l < 2; ++l) {
    int c = tid + l * 256;
    int m = c >> 3, j = c & 7;
    int row = m0 + m;
    uint4 v = make_uint4(0, 0, 0, 0);
    if (row < NN) v = ((const uint4*)(F + (size_t)row * 64))[j];
    int k8 = 8 + j, t = k8 >> 2, kq = k8 & 3;
    int wv = m >> 4, mr = m & 15;
    ((uint4*)sA)[(wv * 4 + t) * 64 + kq * 16 + mr] = v;
  }
  __syncthreads();

  const int w = tid >> 6, L = tid & 63;
  const bf16x8* Af = (const bf16x8*)sA;
  const bf16x8* Bf = (const bf16x8*)Wp;
  f32x4 acc[NF];
#pragma unroll
  for (int i = 0; i < NF; ++i)
#pragma unroll
    for (int j = 0; j < 4; ++j) acc[i][j] = 0.f;
#pragma unroll
  for (int t = 0; t < 4; ++t) {
    bf16x8 afr = Af[(w * 4 + t) * 64 + L];
#pragma unroll
    for (int n0 = 0; n0 < NF; ++n0) {
      bf16x8 bfr = Bf[(n0 * 4 + t) * 64 + L];
      acc[n0] = __builtin_amdgcn_mfma_f32_16x16x32_bf16(afr, bfr, acc[n0], 0, 0, 0);
    }
  }

  int rg = L >> 4, cl = L & 15;
#pragma unroll
  for (int half = 0; half < NF / 4; ++half) {
    __syncthreads();
#pragma unroll
    for (int n0 = 0; n0 < 4; ++n0)
#pragma unroll
      for (int rr = 0; rr < 4; ++rr)
        sC[(w * 16 + rg * 4 + rr) * 66 + n0 * 16 + cl] = acc[half * 4 + n0][rr];
    __syncthreads();
#pragma unroll
    for (int it = 0; it < 2; ++it) {
      int c = tid + it * 256;
      int m = c >> 3, c8 = c & 7;
      int row = m0 + m;
      if (row < NN) {
        float v[8];
#pragma unroll
        for (int j = 0; j < 8; ++j)
          v[j] = fmaxf(sC[m * 66 + c8 * 8 + j] + bias[half * 64 + c8 * 8 + j], 0.f);
        uint4 o;
        o.x = packbf2(v[0], v[1]); o.y = packbf2(v[2], v[3]);
        o.z = packbf2(v[4], v[5]); o.w = packbf2(v[6], v[7]);
        ((uint4*)(OUT + (size_t)row * outStride + half * 64))[c8] = o;
      }
    }
  }
}

// ----------------------------------------------- fused mean-pool + MLP ------
__global__ __launch_bounds__(64) void k_poolmlp(
    const unsigned short* __restrict__ H, const int* __restrict__ gstart,
    const float* __restrict__ w1, const float* __restrict__ b1,
    const float* __restrict__ w2, const float* __restrict__ b2,
    const float* __restrict__ w3, const float* __restrict__ b3,
    const float* __restrict__ w4, const float* __restrict__ b4,
    float* __restrict__ out) {
  __shared__ float sg[64], s1[64], s2[32], s3[32];
  int g = blockIdx.x, t = threadIdx.x;
  int beg = gstart[g], end = gstart[g + 1];
  float a0 = 0.f, a1 = 0.f, a2 = 0.f, a3 = 0.f;
  int n = beg;
  for (; n + 4 <= end; n += 4) {  // 4 rows in flight (coalesced 128B reads)
    a0 += bfs(H[(size_t)n * 64 + t]);
    a1 += bfs(H[(size_t)(n + 1) * 64 + t]);
    a2 += bfs(H[(size_t)(n + 2) * 64 + t]);
    a3 += bfs(H[(size_t)(n + 3) * 64 + t]);
  }
  for (; n < end; ++n) a0 += bfs(H[(size_t)n * 64 + t]);
  float cnt = fmaxf((float)(end - beg), 1.0f);
  sg[t] = ((a0 + a1) + (a2 + a3)) / cnt;
  __syncthreads();
  float acc = b1[t];
  for (int k = 0; k < 64; ++k) acc += sg[k] * w1[k * 64 + t];
  s1[t] = fmaxf(acc, 0.0f);
  __syncthreads();
  if (t < 32) {
    acc = b2[t];
    for (int k = 0; k < 64; ++k) acc += s1[k] * w2[k * 32 + t];
    s2[t] = fmaxf(acc, 0.0f);
  }
  __syncthreads();
  if (t < 32) {
    acc = b3[t];
    for (int k = 0; k < 32; ++k) acc += s2[k] * w3[k * 32 + t];
    s3[t] = fmaxf(acc, 0.0f);
  }
  __syncthreads();
  if (t == 0) {
    acc = b4[0];
    for (int k = 0; k < 32; ++k) acc += s3[k] * w4[k];
    out[g] = acc;
  }
}

// ---------------------------------------------------------------- launch ----
extern "C" void kernel_launch(void* const* d_in, const int* in_sizes, int n_in,
                              void* d_out, int out_size, void* d_ws,
                              size_t ws_size, hipStream_t stream) {
  const float* x     = (const float*)d_in[0];
  const int*   ei    = (const int*)d_in[1];
  const int*   batch = (const int*)d_in[2];
  const int* src = ei;
  const int* dst = ei + NE;

  const float* c1_wl = (const float*)d_in[3];
  const float* c1_bl = (const float*)d_in[4];
  const float* c1_wr = (const float*)d_in[5];
  const float* c2_wl = (const float*)d_in[6];
  const float* c2_bl = (const float*)d_in[7];
  const float* c2_wr = (const float*)d_in[8];
  const float* c3_wl = (const float*)d_in[9];
  const float* c3_bl = (const float*)d_in[10];
  const float* c3_wr = (const float*)d_in[11];
  const float* c4_wl = (const float*)d_in[12];
  const float* c4_bl = (const float*)d_in[13];
  const float* c4_wr = (const float*)d_in[14];
  const float* l1w = (const float*)d_in[15];
  const float* l1b = (const float*)d_in[16];
  const float* l2w = (const float*)d_in[17];
  const float* l2b = (const float*)d_in[18];
  const float* l3w = (const float*)d_in[19];
  const float* l3b = (const float*)d_in[20];
  const float* l4w = (const float*)d_in[21];
  const float* l4b = (const float*)d_in[22];

  // ---- workspace carve-up
  char* wsb = (char*)d_ws;
  unsigned short* xb  = (unsigned short*)wsb;
  unsigned short* B1  = xb + (size_t)NN * 64;    // h2 / h4
  unsigned short* B3  = B1 + (size_t)NN * 64;    // U / h3
  unsigned short* B4  = B3 + (size_t)NN * 64;    // V
  unsigned short* ZZ  = B4 + (size_t)NN * 64;    // x@wr + bias (NN x 128)
  unsigned short* pL1  = ZZ + (size_t)NN * 128;  // 128x128 pack
  unsigned short* pL2a = pL1 + 128 * 128;
  unsigned short* pL2b = pL2a + 128 * 64;
  unsigned short* pL3  = pL2b + 128 * 64;
  unsigned short* pL4  = pL3 + 128 * 64;
  unsigned short* pLZ  = pL4 + 128 * 64;         // 64x128 pack (Z-gemm)
  int* cnt    = (int*)(pLZ + 64 * 128);          // NN*CPAD
  int* gstart = cnt + (size_t)NN * CPAD;         // NG+1
  int* csr    = gstart + NG + 1 + 2;             // NN*MAXDEG (padded CSR)

  const int gN8 = NN * 8 / 256;       // 3125
  const int gM  = (NN + 63) / 64;     // 1563

  // ---- Z-gemm weight pack + cnt zeroing (memset dispatch folded in)
  k_prepz<<<32 + (NN * CPAD / 4 + 255) / 256, 256, 0, stream>>>(c1_wr, pLZ, cnt);

  // ---- merged setup: count+fill groups of 8 blocks (all XCDs) alternating
  //      1:1 with Z-gemm/cvt/bounds/prep groups (compute = atomic dilution)
  k_setup<<<GB_SETUP, 256, 0, stream>>>(src, dst, cnt, csr, x, xb, batch,
                                        gstart, pLZ, c1_bl, ZZ,
                                        c1_wl, c1_wr, c2_wl, c2_wr,
                                        c3_wl, c3_wr, c4_wl, c4_wr,
                                        pL1, pL2a, pL2b, pL3, pL4);

  // ---- layer 1+2a (fused): h1 = relu(agg(x)@WL + ZZ) kept in LDS;
  //      B3 = h1@c2wl, B4 = h1@c2wr written directly (h1 never hits HBM)
  k_fgemm1<<<gM, 256, 0, stream>>>(xb, csr, cnt, pL1, ZZ, pL2a, pL2b, B3, B4);

  // ---- layer 2b: B1(h2) = relu(agg(B3) + b + B4)
  k_gather<<<gN8, 256, 0, stream>>>(B3, csr, cnt, c2_bl, B4, B1);

  // ---- layer 3 (fused): B3(h3) = relu([agg(h2)|h2] @ pL3 + c3_bl)
  k_fgemm<4><<<gM, 256, 0, stream>>>(B1, csr, cnt, pL3, c3_bl, B3, 64);

  // ---- layer 4 (fused): B1(h4) = relu([agg(h3)|h3] @ pL4 + c4_bl)
  k_fgemm<4><<<gM, 256, 0, stream>>>(B3, csr, cnt, pL4, c4_bl, B1, 64);

  // ---- fused pool + MLP
  k_poolmlp<<<NG, 64, 0, stream>>>(B1, gstart, l1w, l1b, l2w, l2b,
                                   l3w, l3b, l4w, l4b, (float*)d_out);
}